// Round 6
// baseline (398.379 us; speedup 1.0000x reference)
//
#include <hip/hip_runtime.h>

#define NN 2048
#define NN2 (NN * NN)

// ---- vector load helpers ----
__device__ __forceinline__ void load6z(const float* __restrict__ A, int i, int j0, float a[6]) {
    if ((unsigned)i >= (unsigned)NN) {
#pragma unroll
        for (int q = 0; q < 6; ++q) a[q] = 0.f;
        return;
    }
    const float* row = A + (size_t)i * NN;
    float4 c = *reinterpret_cast<const float4*>(row + j0);
    a[1] = c.x; a[2] = c.y; a[3] = c.z; a[4] = c.w;
    a[0] = (j0 > 0) ? row[j0 - 1] : 0.f;
    a[5] = (j0 + 4 < NN) ? row[j0 + 4] : 0.f;
}
__device__ __forceinline__ void load4z(const float* __restrict__ A, int i, int j0, float a[4]) {
    if ((unsigned)i >= (unsigned)NN) {
#pragma unroll
        for (int q = 0; q < 4; ++q) a[q] = 0.f;
        return;
    }
    float4 c = *reinterpret_cast<const float4*>(A + (size_t)i * NN + j0);
    a[0] = c.x; a[1] = c.y; a[2] = c.z; a[3] = c.w;
}
__device__ __forceinline__ void load6e(const float* __restrict__ A, int i, int j0, float a[6]) {
    i = i < 0 ? 0 : (i > NN - 1 ? NN - 1 : i);
    const float* row = A + (size_t)i * NN;
    float4 c = *reinterpret_cast<const float4*>(row + j0);
    a[1] = c.x; a[2] = c.y; a[3] = c.z; a[4] = c.w;
    a[0] = (j0 > 0) ? row[j0 - 1] : c.x;
    a[5] = (j0 + 4 < NN) ? row[j0 + 4] : c.w;
}
__device__ __forceinline__ void store4(float* __restrict__ A, int i, int j0, const float a[4]) {
    *reinterpret_cast<float4*>(A + (size_t)i * NN + j0) = make_float4(a[0], a[1], a[2], a[3]);
}

// ===================== fully fused momentum: pg1(u) + predictor + pg1(b) + corrector =====================
// tile 16 rows x 64 cols. Stages: load(u,v,p) -> k(u) -> b -> k(b) -> out.
// LDS strides are odd (73/71/69/67) so the 4 ty-rows of a wave hit disjoint bank groups (2-way max).
__global__ __launch_bounds__(256) void k_mom(const float* __restrict__ u, const float* __restrict__ v,
                                             const float* __restrict__ k1, const float* __restrict__ p,
                                             const float* __restrict__ Fx, const float* __restrict__ Fy,
                                             float* __restrict__ un, float* __restrict__ vn) {
    const float DT = 0.01f;
    __shared__ float su[24][73], sv[24][73];     // u,v rows ib-4..ib+19, cols jb-4..jb+67 (zero-pad)
    __shared__ float sp[22][73];                 // p rows ib-3..ib+18, cols jb-4..jb+67 (edge-pad)
    __shared__ float sku[22][71], skv[22][71];   // k(u) rows ib-3..ib+18, cols jb-3..jb+66
    __shared__ float sbu[20][69], sbv[20][69];   // b rows ib-2..ib+17, cols jb-2..jb+65 (zero outside)
    __shared__ float skbu[18][67], skbv[18][67]; // k(b) rows ib-1..ib+16, cols jb-1..jb+64
    const int jb = blockIdx.x * 64;
    const int ib = blockIdx.y * 16;
    const int tid = threadIdx.y * 16 + threadIdx.x;

    // ---- stage u,v (zero-pad) ----
    for (int idx = tid; idx < 24 * 18; idx += 256) {
        int r = idx / 18, c4 = idx - r * 18;
        int gi = ib - 4 + r;
        int gj = jb - 4 + c4 * 4;
        float tu[4] = {0.f, 0.f, 0.f, 0.f}, tv[4] = {0.f, 0.f, 0.f, 0.f};
        if ((unsigned)gi < (unsigned)NN) {
            if (gj >= 0 && gj + 3 < NN) {
                float4 a = *reinterpret_cast<const float4*>(u + (size_t)gi * NN + gj);
                float4 bq = *reinterpret_cast<const float4*>(v + (size_t)gi * NN + gj);
                tu[0] = a.x; tu[1] = a.y; tu[2] = a.z; tu[3] = a.w;
                tv[0] = bq.x; tv[1] = bq.y; tv[2] = bq.z; tv[3] = bq.w;
            } else {
#pragma unroll
                for (int q = 0; q < 4; ++q) {
                    int g = gj + q;
                    if ((unsigned)g < (unsigned)NN) {
                        tu[q] = u[(size_t)gi * NN + g];
                        tv[q] = v[(size_t)gi * NN + g];
                    }
                }
            }
        }
#pragma unroll
        for (int q = 0; q < 4; ++q) { su[r][c4 * 4 + q] = tu[q]; sv[r][c4 * 4 + q] = tv[q]; }
    }
    // ---- stage p (edge-pad) ----
    for (int idx = tid; idx < 22 * 18; idx += 256) {
        int r = idx / 18, c4 = idx - r * 18;
        int gi = ib - 3 + r;
        gi = gi < 0 ? 0 : (gi > NN - 1 ? NN - 1 : gi);
        int gj = jb - 4 + c4 * 4;
        float tp[4];
        if (gj >= 0 && gj + 3 < NN) {
            float4 a = *reinterpret_cast<const float4*>(p + (size_t)gi * NN + gj);
            tp[0] = a.x; tp[1] = a.y; tp[2] = a.z; tp[3] = a.w;
        } else {
#pragma unroll
            for (int q = 0; q < 4; ++q) {
                int g = gj + q;
                g = g < 0 ? 0 : (g > NN - 1 ? NN - 1 : g);
                tp[q] = p[(size_t)gi * NN + g];
            }
        }
#pragma unroll
        for (int q = 0; q < 4; ++q) sp[r][c4 * 4 + q] = tp[q];
    }
    __syncthreads();

    // ---- k(u) on rows ib-3..ib+18, cols jb-3..jb+66 ----
    for (int idx = tid; idx < 22 * 70; idx += 256) {
        int r = idx / 70, c = idx - r * 70;
        int gi = ib - 3 + r, gj = jb - 3 + c;
        float kuo = 0.f, kvo = 0.f;
        if ((unsigned)gi < (unsigned)NN && (unsigned)gj < (unsigned)NN) {
            int lr = r + 1, lc = c + 1;   // su base (ib-4, jb-4)
            float uc = su[lr][lc], ul = su[lr][lc - 1], ur = su[lr][lc + 1], ut = su[lr - 1][lc], ub = su[lr + 1][lc];
            float vc = sv[lr][lc], vl = sv[lr][lc - 1], vr = sv[lr][lc + 1], vt = sv[lr - 1][lc], vb = sv[lr + 1][lc];
            float ADxu = 0.5f * (ur - ul), ADyu = 0.5f * (ub - ut);
            float ADxv = 0.5f * (vr - vl), ADyv = 0.5f * (vb - vt);
            float Lu = ul + ur + ut + ub - 4.f * uc;
            float Lv = vl + vr + vt + vb - 4.f * vc;
            float s = fabsf(uc) + fabsf(vc);
            float kuv = 0.25f * fabsf(0.5f * s * Lu) / (0.001f + 0.5f * (fabsf(ADxu) + fabsf(ADyu)));
            float kvv = 0.25f * fabsf(0.5f * s * Lv) / (0.001f + 0.5f * (fabsf(ADxv) + fabsf(ADyv)));
            float k1c = k1[(size_t)gi * NN + gj];
            kuo = fminf(kuv, k1c);
            kvo = fminf(kvv, k1c);
        }
        sku[r][c] = kuo;
        skv[r][c] = kvo;
    }
    __syncthreads();

    // ---- predictor b on rows ib-2..ib+17, cols jb-2..jb+65 ----
    for (int idx = tid; idx < 20 * 68; idx += 256) {
        int r = idx / 68, c = idx - r * 68;
        int gi = ib - 2 + r, gj = jb - 2 + c;
        float buo = 0.f, bvo = 0.f;
        if ((unsigned)gi < (unsigned)NN && (unsigned)gj < (unsigned)NN) {
            int lu = r + 2, cu = c + 2;   // su base
            int lk = r + 1, ck = c + 1;   // sku base
            int lp = r + 1, cp = c + 2;   // sp base (ib-3, jb-4)
            float uc = su[lu][cu], ul = su[lu][cu - 1], ur = su[lu][cu + 1], ut = su[lu - 1][cu], ub = su[lu + 1][cu];
            float vc = sv[lu][cu], vl = sv[lu][cu - 1], vr = sv[lu][cu + 1], vt = sv[lu - 1][cu], vb = sv[lu + 1][cu];
            float kuc = sku[lk][ck], kul = sku[lk][ck - 1], kur = sku[lk][ck + 1], kut = sku[lk - 1][ck], kub = sku[lk + 1][ck];
            float kvc = skv[lk][ck], kvl = skv[lk][ck - 1], kvr = skv[lk][ck + 1], kvt = skv[lk - 1][ck], kvb = skv[lk + 1][ck];
            float ADxu = 0.5f * (ur - ul), ADyu = 0.5f * (ub - ut);
            float ADxv = 0.5f * (vr - vl), ADyv = 0.5f * (vb - vt);
            float Lu = ul + ur + ut + ub - 4.f * uc;
            float Lv = vl + vr + vt + vb - 4.f * vc;
            float Lku = kul + kur + kut + kub - 4.f * kuc;
            float Lkv = kvl + kvr + kvt + kvb - 4.f * kvc;
            float Luku = ul * kul + ur * kur + ut * kut + ub * kub - 4.f * uc * kuc;
            float Lvkv = vl * kvl + vr * kvr + vt * kvt + vb * kvb - 4.f * vc * kvc;
            float kx = 1.5f * (kuc * Lu + Luku - uc * Lku);
            float ky = 1.5f * (kvc * Lv + Lvkv - vc * Lkv);
            float Grapx = 0.5f * (sp[lp][cp + 1] - sp[lp][cp - 1]) * DT;
            float Grapy = 0.5f * (sp[lp + 1][cp] - sp[lp - 1][cp]) * DT;
            buo = uc + 0.5f * (kx * DT - uc * ADxu * DT - vc * ADyu * DT) - Grapx;
            bvo = vc + 0.5f * (ky * DT - uc * ADxv * DT - vc * ADyv * DT) - Grapy;
        }
        sbu[r][c] = buo;
        sbv[r][c] = bvo;
    }
    __syncthreads();

    // ---- k(b) on rows ib-1..ib+16, cols jb-1..jb+64 ----
    for (int idx = tid; idx < 18 * 66; idx += 256) {
        int r = idx / 66, c = idx - r * 66;
        int gi = ib - 1 + r, gj = jb - 1 + c;
        float kuo = 0.f, kvo = 0.f;
        if ((unsigned)gi < (unsigned)NN && (unsigned)gj < (unsigned)NN) {
            int lr = r + 1, lc = c + 1;   // sbu base (ib-2, jb-2)
            float uc = sbu[lr][lc], ul = sbu[lr][lc - 1], ur = sbu[lr][lc + 1], ut = sbu[lr - 1][lc], ub = sbu[lr + 1][lc];
            float vc = sbv[lr][lc], vl = sbv[lr][lc - 1], vr = sbv[lr][lc + 1], vt = sbv[lr - 1][lc], vb = sbv[lr + 1][lc];
            float ADxu = 0.5f * (ur - ul), ADyu = 0.5f * (ub - ut);
            float ADxv = 0.5f * (vr - vl), ADyv = 0.5f * (vb - vt);
            float Lu = ul + ur + ut + ub - 4.f * uc;
            float Lv = vl + vr + vt + vb - 4.f * vc;
            float s = fabsf(uc) + fabsf(vc);
            float kuv = 0.25f * fabsf(0.5f * s * Lu) / (0.001f + 0.5f * (fabsf(ADxu) + fabsf(ADyu)));
            float kvv = 0.25f * fabsf(0.5f * s * Lv) / (0.001f + 0.5f * (fabsf(ADxv) + fabsf(ADyv)));
            float k1c = k1[(size_t)gi * NN + gj];
            kuo = fminf(kuv, k1c);
            kvo = fminf(kvv, k1c);
        }
        skbu[r][c] = kuo;
        skbv[r][c] = kvo;
    }
    __syncthreads();

    // ---- corrector outputs ----
    const int i = ib + threadIdx.y;
    const int j0 = jb + threadIdx.x * 4;
    float fx[4], fy[4], oun[4], ovn[4];
    load4z(Fx, i, j0, fx); load4z(Fy, i, j0, fy);
    const int lb = threadIdx.y + 2;   // sbu row
    const int lk = threadIdx.y + 1;   // skb row
    const int lu = threadIdx.y + 4;   // su row
    const int lp = threadIdx.y + 3;   // sp row
#pragma unroll
    for (int c = 0; c < 4; ++c) {
        int cb = threadIdx.x * 4 + c + 2;
        int ck = threadIdx.x * 4 + c + 1;
        int cu = threadIdx.x * 4 + c + 4;
        float buc = sbu[lb][cb], bul = sbu[lb][cb - 1], bur = sbu[lb][cb + 1], but = sbu[lb - 1][cb], bub = sbu[lb + 1][cb];
        float bvc = sbv[lb][cb], bvl = sbv[lb][cb - 1], bvr = sbv[lb][cb + 1], bvt = sbv[lb - 1][cb], bvb = sbv[lb + 1][cb];
        float kuc = skbu[lk][ck], kul = skbu[lk][ck - 1], kur = skbu[lk][ck + 1], kut = skbu[lk - 1][ck], kub = skbu[lk + 1][ck];
        float kvc = skbv[lk][ck], kvl = skbv[lk][ck - 1], kvr = skbv[lk][ck + 1], kvt = skbv[lk - 1][ck], kvb = skbv[lk + 1][ck];
        float uc = su[lu][cu], ul = su[lu][cu - 1], ur = su[lu][cu + 1], ut = su[lu - 1][cu], ub = su[lu + 1][cu];
        float vc = sv[lu][cu], vl = sv[lu][cu - 1], vr = sv[lu][cu + 1], vt = sv[lu - 1][cu], vb = sv[lu + 1][cu];
        float ADxbu = 0.5f * (bur - bul), ADybu = 0.5f * (bub - but);
        float ADxbv = 0.5f * (bvr - bvl), ADybv = 0.5f * (bvb - bvt);
        float Lbu = bul + bur + but + bub - 4.f * buc;
        float Lbv = bvl + bvr + bvt + bvb - 4.f * bvc;
        float Lku = kul + kur + kut + kub - 4.f * kuc;
        float Lkv = kvl + kvr + kvt + kvb - 4.f * kvc;
        // product term uses ORIGINAL velocities
        float Luku = ul * kul + ur * kur + ut * kut + ub * kub - 4.f * uc * kuc;
        float Lvkv = vl * kvl + vr * kvr + vt * kvt + vb * kvb - 4.f * vc * kvc;
        float kx = 1.5f * (kuc * Lbu + Luku - buc * Lku);
        float ky = 1.5f * (kvc * Lbv + Lvkv - bvc * Lkv);
        float Grapx = 0.5f * (sp[lp][cu + 1] - sp[lp][cu - 1]) * DT;
        float Grapy = 0.5f * (sp[lp + 1][cu] - sp[lp - 1][cu]) * DT;
        oun[c] = uc + kx * DT - buc * ADxbu * DT - bvc * ADybu * DT - Grapx - fx[c] * DT;
        ovn[c] = vc + ky * DT - buc * ADxbv * DT - bvc * ADybv * DT - Grapy - fy[c] * DT;
    }
    store4(un, i, j0, oun);
    store4(vn, i, j0, ovn);
}

// -------- fused: b = -div(un,vn)/DT + residual(p,b) + restrict to 1024/512/256 --------
__global__ __launch_bounds__(256) void k_rhs_res(const float* __restrict__ un, const float* __restrict__ vn,
                                                 const float* __restrict__ p, float* __restrict__ b,
                                                 float* __restrict__ r1024, float* __restrict__ r512,
                                                 float* __restrict__ r256) {
    __shared__ float s512r[4][65];
    int tx = threadIdx.x, ty = threadIdx.y;
    int jt = blockIdx.x * 64 + tx;
    int it = blockIdx.y * 4 + ty;
    int j0 = jt * 4, i0 = it * 4;
    float bb[4][4];
#pragma unroll
    for (int r = 0; r < 4; ++r) {
        float u6[6], vu[4], vd[4];
        load6z(un, i0 + r, j0, u6);
        load4z(vn, i0 + r - 1, j0, vu);
        load4z(vn, i0 + r + 1, j0, vd);
#pragma unroll
        for (int c = 0; c < 4; ++c)
            bb[r][c] = -100.f * (0.5f * (u6[c + 2] - u6[c]) + 0.5f * (vd[c] - vu[c]));
        store4(b, i0 + r, j0, bb[r]);
    }
    float p6[6][6];
#pragma unroll
    for (int r = 0; r < 6; ++r) load6e(p, i0 - 1 + r, j0, p6[r]);
    float res[4][4];
#pragma unroll
    for (int r = 0; r < 4; ++r)
#pragma unroll
        for (int c = 0; c < 4; ++c) {
            float pc = p6[r + 1][c + 1];
            res[r][c] = p6[r][c + 1] + p6[r + 2][c + 1] + p6[r + 1][c] + p6[r + 1][c + 2] - 4.f * pc - bb[r][c];
        }
    float q00 = 0.25f * (res[0][0] + res[0][1] + res[1][0] + res[1][1]);
    float q01 = 0.25f * (res[0][2] + res[0][3] + res[1][2] + res[1][3]);
    float q10 = 0.25f * (res[2][0] + res[2][1] + res[3][0] + res[3][1]);
    float q11 = 0.25f * (res[2][2] + res[2][3] + res[3][2] + res[3][3]);
    int ci = it * 2, cj = jt * 2;
    *reinterpret_cast<float2*>(r1024 + (size_t)ci * 1024 + cj)       = make_float2(q00, q01);
    *reinterpret_cast<float2*>(r1024 + (size_t)(ci + 1) * 1024 + cj) = make_float2(q10, q11);
    float s = 0.25f * (q00 + q01 + q10 + q11);
    r512[(size_t)it * 512 + jt] = s;
    s512r[ty][tx] = s;
    __syncthreads();
    int tid = ty * 64 + tx;
    if (tid < 64) {
        int a = tid >> 5, c = tid & 31;
        float m = 0.25f * (s512r[2 * a][2 * c] + s512r[2 * a][2 * c + 1] + s512r[2 * a + 1][2 * c] + s512r[2 * a + 1][2 * c + 1]);
        r256[(size_t)(blockIdx.y * 2 + a) * 256 + blockIdx.x * 32 + c] = m;
    }
}

// ---------------- coarse levels: r256 -> (r128 out) -> ... -> w128, r2 ----------------
__global__ __launch_bounds__(1024) void k_small2(const float* __restrict__ r256in,
                                                 float* __restrict__ r128g,
                                                 float* __restrict__ w128_out,
                                                 float* __restrict__ r2_out) {
    __shared__ float sr128[128 * 128];
    __shared__ float sr64[64 * 64];
    __shared__ float sr32[32 * 32];
    __shared__ float sr16[16 * 16];
    __shared__ float sr8[8 * 8];
    __shared__ float sr4[16];
    __shared__ float sr2[4];
    __shared__ float wa[64 * 64];
    __shared__ float wb[64 * 64];
    int t = threadIdx.x;

    for (int idx = t; idx < 128 * 128; idx += 1024) {
        int i = idx >> 7, j = idx & 127;
        const float* s0 = r256in + (2 * i) * 256 + 2 * j;
        float m = 0.25f * (s0[0] + s0[1] + s0[256] + s0[257]);
        sr128[idx] = m;
        r128g[idx] = m;
    }
    __syncthreads();
    for (int idx = t; idx < 64 * 64; idx += 1024) {
        int i = idx >> 6, j = idx & 63;
        const float* s0 = sr128 + (2 * i) * 128 + 2 * j;
        sr64[idx] = 0.25f * (s0[0] + s0[1] + s0[128] + s0[129]);
    }
    __syncthreads();
    if (t < 32 * 32) {
        int i = t >> 5, j = t & 31;
        const float* s0 = sr64 + (2 * i) * 64 + 2 * j;
        sr32[t] = 0.25f * (s0[0] + s0[1] + s0[64] + s0[65]);
    }
    __syncthreads();
    if (t < 16 * 16) {
        int i = t >> 4, j = t & 15;
        const float* s0 = sr32 + (2 * i) * 32 + 2 * j;
        sr16[t] = 0.25f * (s0[0] + s0[1] + s0[32] + s0[33]);
    }
    __syncthreads();
    if (t < 64) {
        int i = t >> 3, j = t & 7;
        const float* s0 = sr16 + (2 * i) * 16 + 2 * j;
        sr8[t] = 0.25f * (s0[0] + s0[1] + s0[16] + s0[17]);
    }
    __syncthreads();
    if (t < 16) {
        int i = t >> 2, j = t & 3;
        const float* s0 = sr8 + (2 * i) * 8 + 2 * j;
        sr4[t] = 0.25f * (s0[0] + s0[1] + s0[8] + s0[9]);
    }
    __syncthreads();
    if (t < 4) {
        int i = t >> 1, j = t & 1;
        const float* s0 = sr4 + (2 * i) * 4 + 2 * j;
        sr2[t] = 0.25f * (s0[0] + s0[1] + s0[4] + s0[5]);
        r2_out[t] = sr2[t];
        float ws = -0.25f * sr2[t];
        wa[(2 * i) * 4 + 2 * j] = ws;
        wa[(2 * i) * 4 + 2 * j + 1] = ws;
        wa[(2 * i + 1) * 4 + 2 * j] = ws;
        wa[(2 * i + 1) * 4 + 2 * j + 1] = ws;
    }
    __syncthreads();

    auto step = [&](const float* win, const float* rl, float* wout, int s) {
        for (int idx = t; idx < s * s; idx += 1024) {
            int i = idx / s, j = idx - i * s;
            float up = i > 0 ? win[(i - 1) * s + j] : 0.f;
            float dn = i < s - 1 ? win[(i + 1) * s + j] : 0.f;
            float lf = j > 0 ? win[i * s + j - 1] : 0.f;
            float rt = j < s - 1 ? win[i * s + j + 1] : 0.f;
            float ws = 0.25f * (up + dn + lf + rt - rl[idx]);
            int o = 2 * s;
            wout[(2 * i) * o + 2 * j] = ws;
            wout[(2 * i) * o + 2 * j + 1] = ws;
            wout[(2 * i + 1) * o + 2 * j] = ws;
            wout[(2 * i + 1) * o + 2 * j + 1] = ws;
        }
    };
    step(wa, sr4, wb, 4);
    __syncthreads();
    step(wb, sr8, wa, 8);
    __syncthreads();
    step(wa, sr16, wb, 16);
    __syncthreads();
    step(wb, sr32, wa, 32);
    __syncthreads();
    step(wa, sr64, w128_out, 64);
}

// ======== fused p-update: (w128,r128,r256,r512,r1024) -> S128..S1024 in LDS -> p_new (+halo)
//          + next residual + restrict 1024/512/256  (LAST: out_p/out_w + projection) ========
template <bool LAST>
__global__ __launch_bounds__(256) void k_pupd4(
    const float* __restrict__ p, const float* __restrict__ b,
    const float* __restrict__ w128, const float* __restrict__ r128,
    const float* __restrict__ r256, const float* __restrict__ r512,
    const float* __restrict__ r1024,
    float* __restrict__ pdst,
    float* __restrict__ o1024, float* __restrict__ o512, float* __restrict__ o256,
    float* __restrict__ wout, float* __restrict__ un, float* __restrict__ vn)
{
    __shared__ float sw[5][15];       // w128 tile
    __shared__ float s128[3][13];     // S128 smooth
    __shared__ float s256[3][21];     // S256 smooth
    __shared__ float sS[4][37];       // S512 smooth
    __shared__ float ws[6][69];       // S1024 smooth
    __shared__ float pmid[12][137];
    __shared__ float pnew[10][131];
    __shared__ float sq[4][65];
    __shared__ float red[2][33];

    const int jb = blockIdx.x * 128;
    const int ib = blockIdx.y * 8;
    const int tid = threadIdx.y * 32 + threadIdx.x;
    const int r1 = ib / 2 - 1,  c1 = jb / 2 - 2;   // ws rows 6, cols 68
    const int r2 = ib / 4 - 1,  c2 = jb / 4 - 2;   // sS rows 4, cols 36
    const int r3 = ib / 8 - 1,  c3 = jb / 8 - 2;   // s256 rows 3, cols 20
    const int r4 = ib / 16 - 1, c4 = jb / 16 - 2;  // s128 rows 3, cols 12
    const int r5 = ib / 16 - 2, c5 = jb / 16 - 3;  // sw rows 5, cols 14

    if (tid < 5 * 14) {
        int r = tid / 14, c = tid - (tid / 14) * 14;
        int x = r5 + r, y = c5 + c;
        sw[r][c] = ((unsigned)x < 128u && (unsigned)y < 128u) ? w128[x * 128 + y] : 0.f;
    }
    __syncthreads();
    if (tid < 3 * 12) {
        int r = tid / 12, c = tid - (tid / 12) * 12;
        int x = r4 + r, y = c4 + c;
        float val = 0.f;
        if ((unsigned)x < 128u && (unsigned)y < 128u) {
            int lr = x - r5, lc = y - c5;
            float s = 0.f;
            if (x > 0)   s += sw[lr - 1][lc];
            if (x < 127) s += sw[lr + 1][lc];
            if (y > 0)   s += sw[lr][lc - 1];
            if (y < 127) s += sw[lr][lc + 1];
            val = 0.25f * (s - r128[x * 128 + y]);
        }
        s128[r][c] = val;
    }
    __syncthreads();
    if (tid < 3 * 20) {
        int r = tid / 20, c = tid - (tid / 20) * 20;
        int x = r3 + r, y = c3 + c;
        float val = 0.f;
        if ((unsigned)x < 256u && (unsigned)y < 256u) {
            float s = 0.f;
            if (x > 0)   s += s128[((x - 1) >> 1) - r4][(y >> 1) - c4];
            if (x < 255) s += s128[((x + 1) >> 1) - r4][(y >> 1) - c4];
            if (y > 0)   s += s128[(x >> 1) - r4][((y - 1) >> 1) - c4];
            if (y < 255) s += s128[(x >> 1) - r4][((y + 1) >> 1) - c4];
            val = 0.25f * (s - r256[x * 256 + y]);
        }
        s256[r][c] = val;
    }
    __syncthreads();
    if (tid < 4 * 36) {
        int r = tid / 36, c = tid - (tid / 36) * 36;
        int x = r2 + r, y = c2 + c;
        float val = 0.f;
        if ((unsigned)x < 512u && (unsigned)y < 512u) {
            float s = 0.f;
            if (x > 0)   s += s256[((x - 1) >> 1) - r3][(y >> 1) - c3];
            if (x < 511) s += s256[((x + 1) >> 1) - r3][(y >> 1) - c3];
            if (y > 0)   s += s256[(x >> 1) - r3][((y - 1) >> 1) - c3];
            if (y < 511) s += s256[(x >> 1) - r3][((y + 1) >> 1) - c3];
            val = 0.25f * (s - r512[(size_t)x * 512 + y]);
        }
        sS[r][c] = val;
    }
    __syncthreads();
    for (int idx = tid; idx < 6 * 68; idx += 256) {
        int r = idx / 68, c = idx - r * 68;
        int x = r1 + r, y = c1 + c;
        float val = 0.f;
        if ((unsigned)x < 1024u && (unsigned)y < 1024u) {
            float s = 0.f;
            if (x > 0)    s += sS[((x - 1) >> 1) - r2][(y >> 1) - c2];
            if (x < 1023) s += sS[((x + 1) >> 1) - r2][(y >> 1) - c2];
            if (y > 0)    s += sS[(x >> 1) - r2][((y - 1) >> 1) - c2];
            if (y < 1023) s += sS[(x >> 1) - r2][((y + 1) >> 1) - c2];
            val = 0.25f * (s - r1024[(size_t)x * 1024 + y]);
        }
        ws[r][c] = val;
    }
    __syncthreads();
    // pmid = p - up(S1024s): rows ib-2..ib+9, cols jb-4..jb+131 (valid jb-2..jb+129)
    for (int idx = tid; idx < 12 * 34; idx += 256) {
        int r = idx / 34, q = idx - r * 34;
        int gi = ib - 2 + r;
        int gj0 = jb - 4 + q * 4;
        float vals[4] = {0.f, 0.f, 0.f, 0.f};
        if ((unsigned)gi < (unsigned)NN) {
            if (gj0 >= 0 && gj0 + 3 < NN) {
                float4 pv = *reinterpret_cast<const float4*>(p + (size_t)gi * NN + gj0);
                vals[0] = pv.x; vals[1] = pv.y; vals[2] = pv.z; vals[3] = pv.w;
            } else {
#pragma unroll
                for (int q4 = 0; q4 < 4; ++q4) {
                    int gj = gj0 + q4;
                    vals[q4] = ((unsigned)gj < (unsigned)NN) ? p[(size_t)gi * NN + gj] : 0.f;
                }
            }
        }
#pragma unroll
        for (int q4 = 0; q4 < 4; ++q4) {
            int gj = gj0 + q4;
            float m = 0.f;
            if ((unsigned)gi < (unsigned)NN && (unsigned)gj < (unsigned)NN &&
                gj >= jb - 2 && gj <= jb + 129) {
                m = vals[q4] - ws[(gi >> 1) - r1][(gj >> 1) - c1];
            }
            pmid[r][q * 4 + q4] = m;
        }
    }
    __syncthreads();
    // p_new = 0.25*(edge-sum(pmid) - b): rows ib-1..ib+8, cols jb-1..jb+128
    for (int idx = tid; idx < 10 * 130; idx += 256) {
        int r = idx / 130, c = idx - r * 130;
        int gi = ib - 1 + r, gj = jb - 1 + c;
        float val = 0.f;
        if ((unsigned)gi < (unsigned)NN && (unsigned)gj < (unsigned)NN) {
            int iu = gi > 0 ? gi - 1 : 0;
            int idn = gi < NN - 1 ? gi + 1 : NN - 1;
            int jl = gj > 0 ? gj - 1 : 0;
            int jr = gj < NN - 1 ? gj + 1 : NN - 1;
            float s = pmid[iu - (ib - 2)][gj - (jb - 4)] + pmid[idn - (ib - 2)][gj - (jb - 4)]
                    + pmid[gi - (ib - 2)][jl - (jb - 4)] + pmid[gi - (ib - 2)][jr - (jb - 4)];
            val = 0.25f * (s - b[(size_t)gi * NN + gj]);
        }
        pnew[r][c] = val;
    }
    __syncthreads();

    const int i  = ib + threadIdx.y;      // 8 rows
    const int j0 = jb + threadIdx.x * 4;  // 128 cols
    const int lr = i - (ib - 1);
    const int lc = j0 - (jb - 1);
    *reinterpret_cast<float4*>(pdst + (size_t)i * NN + j0) =
        make_float4(pnew[lr][lc], pnew[lr][lc + 1], pnew[lr][lc + 2], pnew[lr][lc + 3]);

    if (LAST) {
        const float DT = 0.01f;
        float ow[4];
        int wr = (i >> 1) - r1;
#pragma unroll
        for (int c = 0; c < 4; ++c) ow[c] = ws[wr][((j0 + c) >> 1) - c1];
        store4(wout, i, j0, ow);
        float4 uu = *reinterpret_cast<float4*>(un + (size_t)i * NN + j0);
        float4 vv = *reinterpret_cast<float4*>(vn + (size_t)i * NN + j0);
        float ou[4] = {uu.x, uu.y, uu.z, uu.w};
        float ov[4] = {vv.x, vv.y, vv.z, vv.w};
        int iu = (i > 0 ? i - 1 : 0) - (ib - 1);
        int idn = (i < NN - 1 ? i + 1 : NN - 1) - (ib - 1);
#pragma unroll
        for (int c = 0; c < 4; ++c) {
            int j = j0 + c;
            int jl = (j > 0 ? j - 1 : 0) - (jb - 1);
            int jr = (j < NN - 1 ? j + 1 : NN - 1) - (jb - 1);
            int lcc = j - (jb - 1);
            ou[c] -= 0.5f * (pnew[lr][jr] - pnew[lr][jl]) * DT;
            ov[c] -= 0.5f * (pnew[idn][lcc] - pnew[iu][lcc]) * DT;
        }
        store4(un, i, j0, ou);
        store4(vn, i, j0, ov);
    } else {
        // next residual on p_new + restrict: 4x64 coarse-1024 points, 1/thread
        int cr = tid >> 6, cc = tid & 63;
        float q = 0.f;
#pragma unroll
        for (int dr = 0; dr < 2; ++dr) {
#pragma unroll
            for (int dc = 0; dc < 2; ++dc) {
                int i2 = ib + 2 * cr + dr, j2 = jb + 2 * cc + dc;
                int lr2 = i2 - (ib - 1), lc2 = j2 - (jb - 1);
                int iu2 = (i2 > 0 ? i2 - 1 : 0) - (ib - 1);
                int id2 = (i2 < NN - 1 ? i2 + 1 : NN - 1) - (ib - 1);
                int jl2 = (j2 > 0 ? j2 - 1 : 0) - (jb - 1);
                int jr2 = (j2 < NN - 1 ? j2 + 1 : NN - 1) - (jb - 1);
                q += pnew[iu2][lc2] + pnew[id2][lc2] + pnew[lr2][jl2] + pnew[lr2][jr2]
                   - 4.f * pnew[lr2][lc2] - b[(size_t)i2 * NN + j2];
            }
        }
        q *= 0.25f;
        sq[cr][cc] = q;
        o1024[(size_t)(ib / 2 + cr) * 1024 + jb / 2 + cc] = q;
        __syncthreads();
        if (tid < 64) {
            int rr = tid >> 5, c5c = tid & 31;
            float m = 0.25f * (sq[2 * rr][2 * c5c] + sq[2 * rr][2 * c5c + 1] +
                               sq[2 * rr + 1][2 * c5c] + sq[2 * rr + 1][2 * c5c + 1]);
            o512[(size_t)(ib / 4 + rr) * 512 + jb / 4 + c5c] = m;
            red[rr][c5c] = m;
        }
        __syncthreads();
        if (tid < 16) {
            float m = 0.25f * (red[0][2 * tid] + red[0][2 * tid + 1] +
                               red[1][2 * tid] + red[1][2 * tid + 1]);
            o256[(size_t)(ib / 8) * 256 + jb / 8 + tid] = m;
        }
    }
}

extern "C" void kernel_launch(void* const* d_in, const int* in_sizes, int n_in,
                              void* d_out, int out_size, void* d_ws, size_t ws_size,
                              hipStream_t stream) {
    const float* u  = (const float*)d_in[0];
    const float* v  = (const float*)d_in[1];
    const float* p  = (const float*)d_in[2];
    const float* Fx = (const float*)d_in[3];
    const float* Fy = (const float*)d_in[4];
    const float* k1 = (const float*)d_in[5];

    float* out = (float*)d_out;
    float* out_u = out;
    float* out_v = out + (size_t)NN2;
    float* out_p = out + 2 * (size_t)NN2;
    float* out_w = out + 3 * (size_t)NN2;
    float* out_r = out + 4 * (size_t)NN2;

    float* wsb = (float*)d_ws;
    float* b  = wsb;
    float* pA = wsb + (size_t)NN2;
    float* pB = wsb + 2 * (size_t)NN2;
    float* base = wsb + 3 * (size_t)NN2;
    float* rA1024 = base;
    float* rA512  = rA1024 + 1024 * 1024;
    float* rA256  = rA512 + 512 * 512;
    float* rB1024 = rA256 + 256 * 256;
    float* rB512  = rB1024 + 1024 * 1024;
    float* rB256  = rB512 + 512 * 512;
    float* r128   = rB256 + 256 * 256;
    float* w128   = r128 + 128 * 128;

    dim3 blkT(16, 16);
    dim3 gT(32, 128);       // k_mom: 64x16 tiles
    dim3 blkR(64, 4);
    dim3 gR(8, 128);        // rhs_res
    dim3 blkP(32, 8);
    dim3 gP(16, 256);       // pupd4: 128x8 fine tiles

    // fused momentum (pred + corr, no bu/bv round-trip)
    k_mom<<<gT, blkT, 0, stream>>>(u, v, k1, p, Fx, Fy, out_u, out_v);
    // b + initial residual pyramid (A)
    k_rhs_res<<<gR, blkR, 0, stream>>>(out_u, out_v, p, b, rA1024, rA512, rA256);

    const float* pcur = p;
    for (int it = 0; it < 5; ++it) {
        const bool useA = (it % 2 == 0);
        const float* R1024 = useA ? rA1024 : rB1024;
        const float* R512  = useA ? rA512  : rB512;
        const float* R256  = useA ? rA256  : rB256;
        float* O1024 = useA ? rB1024 : rA1024;
        float* O512  = useA ? rB512  : rA512;
        float* O256  = useA ? rB256  : rA256;

        k_small2<<<1, 1024, 0, stream>>>(R256, r128, w128, out_r);
        if (it < 4) {
            float* pdst = (it & 1) ? pB : pA;
            k_pupd4<false><<<gP, blkP, 0, stream>>>(pcur, b, w128, r128, R256, R512, R1024,
                                                    pdst, O1024, O512, O256,
                                                    nullptr, nullptr, nullptr);
            pcur = pdst;
        } else {
            k_pupd4<true><<<gP, blkP, 0, stream>>>(pcur, b, w128, r128, R256, R512, R1024,
                                                   out_p, nullptr, nullptr, nullptr,
                                                   out_w, out_u, out_v);
        }
    }
}

// Round 7
// 377.401 us; speedup vs baseline: 1.0556x; 1.0556x over previous
//
#include <hip/hip_runtime.h>

#define NN 2048
#define NN2 (NN * NN)

// ---- vector load helpers ----
__device__ __forceinline__ void load6z(const float* __restrict__ A, int i, int j0, float a[6]) {
    if ((unsigned)i >= (unsigned)NN) {
#pragma unroll
        for (int q = 0; q < 6; ++q) a[q] = 0.f;
        return;
    }
    const float* row = A + (size_t)i * NN;
    float4 c = *reinterpret_cast<const float4*>(row + j0);
    a[1] = c.x; a[2] = c.y; a[3] = c.z; a[4] = c.w;
    a[0] = (j0 > 0) ? row[j0 - 1] : 0.f;
    a[5] = (j0 + 4 < NN) ? row[j0 + 4] : 0.f;
}
__device__ __forceinline__ void load4z(const float* __restrict__ A, int i, int j0, float a[4]) {
    if ((unsigned)i >= (unsigned)NN) {
#pragma unroll
        for (int q = 0; q < 4; ++q) a[q] = 0.f;
        return;
    }
    float4 c = *reinterpret_cast<const float4*>(A + (size_t)i * NN + j0);
    a[0] = c.x; a[1] = c.y; a[2] = c.z; a[3] = c.w;
}
__device__ __forceinline__ void load6e(const float* __restrict__ A, int i, int j0, float a[6]) {
    i = i < 0 ? 0 : (i > NN - 1 ? NN - 1 : i);
    const float* row = A + (size_t)i * NN;
    float4 c = *reinterpret_cast<const float4*>(row + j0);
    a[1] = c.x; a[2] = c.y; a[3] = c.z; a[4] = c.w;
    a[0] = (j0 > 0) ? row[j0 - 1] : c.x;
    a[5] = (j0 + 4 < NN) ? row[j0 + 4] : c.w;
}
__device__ __forceinline__ void load4e(const float* __restrict__ A, int i, int j0, float a[4]) {
    i = i < 0 ? 0 : (i > NN - 1 ? NN - 1 : i);
    float4 c = *reinterpret_cast<const float4*>(A + (size_t)i * NN + j0);
    a[0] = c.x; a[1] = c.y; a[2] = c.z; a[3] = c.w;
}
__device__ __forceinline__ void store4(float* __restrict__ A, int i, int j0, const float a[4]) {
    *reinterpret_cast<float4*>(A + (size_t)i * NN + j0) = make_float4(a[0], a[1], a[2], a[3]);
}

// ===================== fused pg1 + predictor (16-row tile, odd LDS strides) =====================
__global__ __launch_bounds__(256) void k_pred_f(const float* __restrict__ u, const float* __restrict__ v,
                                                const float* __restrict__ k1, const float* __restrict__ p,
                                                float* __restrict__ bu, float* __restrict__ bv) {
    const float DT = 0.01f;
    __shared__ float su[20][73], sv[20][73];   // odd stride: ty-rows hit distinct bank residues mod 4
    __shared__ float sku[18][69], skv[18][69];
    const int jb = blockIdx.x * 64;
    const int ib = blockIdx.y * 16;
    const int tid = threadIdx.y * 16 + threadIdx.x;

    // stage u,v rows ib-2..ib+17, cols jb-4..jb+67 (zero-pad); scalar LDS stores (odd stride)
    for (int idx = tid; idx < 20 * 18; idx += 256) {
        int r = idx / 18, c4 = idx - r * 18;
        int gi = ib - 2 + r;
        int gj = jb - 4 + c4 * 4;
        float tu[4] = {0.f, 0.f, 0.f, 0.f}, tv[4] = {0.f, 0.f, 0.f, 0.f};
        if ((unsigned)gi < (unsigned)NN) {
            if (gj >= 0 && gj + 3 < NN) {
                float4 a = *reinterpret_cast<const float4*>(u + (size_t)gi * NN + gj);
                float4 bq = *reinterpret_cast<const float4*>(v + (size_t)gi * NN + gj);
                tu[0] = a.x; tu[1] = a.y; tu[2] = a.z; tu[3] = a.w;
                tv[0] = bq.x; tv[1] = bq.y; tv[2] = bq.z; tv[3] = bq.w;
            } else {
#pragma unroll
                for (int q = 0; q < 4; ++q) {
                    int g = gj + q;
                    if ((unsigned)g < (unsigned)NN) {
                        tu[q] = u[(size_t)gi * NN + g];
                        tv[q] = v[(size_t)gi * NN + g];
                    }
                }
            }
        }
#pragma unroll
        for (int q = 0; q < 4; ++q) { su[r][c4 * 4 + q] = tu[q]; sv[r][c4 * 4 + q] = tv[q]; }
    }
    __syncthreads();

    // k on rows ib-1..ib+16 (18), cols jb-1..jb+64 (66)
    for (int idx = tid; idx < 18 * 66; idx += 256) {
        int r = idx / 66, c = idx - r * 66;
        int gi = ib - 1 + r, gj = jb - 1 + c;
        float kuo = 0.f, kvo = 0.f;
        if ((unsigned)gi < (unsigned)NN && (unsigned)gj < (unsigned)NN) {
            int lr = r + 1, lc = c + 3;
            float uc = su[lr][lc], ul = su[lr][lc - 1], ur = su[lr][lc + 1], ut = su[lr - 1][lc], ub = su[lr + 1][lc];
            float vc = sv[lr][lc], vl = sv[lr][lc - 1], vr = sv[lr][lc + 1], vt = sv[lr - 1][lc], vb = sv[lr + 1][lc];
            float ADxu = 0.5f * (ur - ul), ADyu = 0.5f * (ub - ut);
            float ADxv = 0.5f * (vr - vl), ADyv = 0.5f * (vb - vt);
            float Lu = ul + ur + ut + ub - 4.f * uc;
            float Lv = vl + vr + vt + vb - 4.f * vc;
            float s = fabsf(uc) + fabsf(vc);
            float kuv = 0.25f * fabsf(0.5f * s * Lu) / (0.001f + 0.5f * (fabsf(ADxu) + fabsf(ADyu)));
            float kvv = 0.25f * fabsf(0.5f * s * Lv) / (0.001f + 0.5f * (fabsf(ADxv) + fabsf(ADyv)));
            float k1c = k1[(size_t)gi * NN + gj];
            kuo = fminf(kuv, k1c);
            kvo = fminf(kvv, k1c);
        }
        sku[r][c] = kuo;
        skv[r][c] = kvo;
    }
    __syncthreads();

    const int i = ib + threadIdx.y;
    const int j0 = jb + threadIdx.x * 4;
    float p6[6], pu[4], pd[4], obu[4], obv[4];
    load6e(p, i, j0, p6); load4e(p, i - 1, j0, pu); load4e(p, i + 1, j0, pd);
    const int lur = threadIdx.y + 2, lkr = threadIdx.y + 1;
#pragma unroll
    for (int c = 0; c < 4; ++c) {
        int luc = threadIdx.x * 4 + c + 4, lkc = threadIdx.x * 4 + c + 1;
        float uc = su[lur][luc], ul = su[lur][luc - 1], ur = su[lur][luc + 1], ut = su[lur - 1][luc], ub = su[lur + 1][luc];
        float vc = sv[lur][luc], vl = sv[lur][luc - 1], vr = sv[lur][luc + 1], vt = sv[lur - 1][luc], vb = sv[lur + 1][luc];
        float kuc = sku[lkr][lkc], kul = sku[lkr][lkc - 1], kur = sku[lkr][lkc + 1], kut = sku[lkr - 1][lkc], kub = sku[lkr + 1][lkc];
        float kvc = skv[lkr][lkc], kvl = skv[lkr][lkc - 1], kvr = skv[lkr][lkc + 1], kvt = skv[lkr - 1][lkc], kvb = skv[lkr + 1][lkc];
        float ADxu = 0.5f * (ur - ul), ADyu = 0.5f * (ub - ut);
        float ADxv = 0.5f * (vr - vl), ADyv = 0.5f * (vb - vt);
        float Lu = ul + ur + ut + ub - 4.f * uc;
        float Lv = vl + vr + vt + vb - 4.f * vc;
        float Lku = kul + kur + kut + kub - 4.f * kuc;
        float Lkv = kvl + kvr + kvt + kvb - 4.f * kvc;
        float Luku = ul * kul + ur * kur + ut * kut + ub * kub - 4.f * uc * kuc;
        float Lvkv = vl * kvl + vr * kvr + vt * kvt + vb * kvb - 4.f * vc * kvc;
        float kx = 1.5f * (kuc * Lu + Luku - uc * Lku);
        float ky = 1.5f * (kvc * Lv + Lvkv - vc * Lkv);
        float Grapx = 0.5f * (p6[c + 2] - p6[c]) * DT;
        float Grapy = 0.5f * (pd[c] - pu[c]) * DT;
        obu[c] = uc + 0.5f * (kx * DT - uc * ADxu * DT - vc * ADyu * DT) - Grapx;
        obv[c] = vc + 0.5f * (ky * DT - uc * ADxv * DT - vc * ADyv * DT) - Grapy;
    }
    store4(bu, i, j0, obu);
    store4(bv, i, j0, obv);
}

// ===================== fused pg1(b) + corrector (16-row tile, odd LDS strides) =====================
__global__ __launch_bounds__(256) void k_corr_f(const float* __restrict__ u, const float* __restrict__ v,
                                                const float* __restrict__ k1, const float* __restrict__ p,
                                                const float* __restrict__ bu, const float* __restrict__ bv,
                                                const float* __restrict__ Fx, const float* __restrict__ Fy,
                                                float* __restrict__ un, float* __restrict__ vn) {
    const float DT = 0.01f;
    __shared__ float sbu[20][73], sbv[20][73];
    __shared__ float sku[18][69], skv[18][69];
    const int jb = blockIdx.x * 64;
    const int ib = blockIdx.y * 16;
    const int tid = threadIdx.y * 16 + threadIdx.x;

    for (int idx = tid; idx < 20 * 18; idx += 256) {
        int r = idx / 18, c4 = idx - r * 18;
        int gi = ib - 2 + r;
        int gj = jb - 4 + c4 * 4;
        float tu[4] = {0.f, 0.f, 0.f, 0.f}, tv[4] = {0.f, 0.f, 0.f, 0.f};
        if ((unsigned)gi < (unsigned)NN) {
            if (gj >= 0 && gj + 3 < NN) {
                float4 a = *reinterpret_cast<const float4*>(bu + (size_t)gi * NN + gj);
                float4 bq = *reinterpret_cast<const float4*>(bv + (size_t)gi * NN + gj);
                tu[0] = a.x; tu[1] = a.y; tu[2] = a.z; tu[3] = a.w;
                tv[0] = bq.x; tv[1] = bq.y; tv[2] = bq.z; tv[3] = bq.w;
            } else {
#pragma unroll
                for (int q = 0; q < 4; ++q) {
                    int g = gj + q;
                    if ((unsigned)g < (unsigned)NN) {
                        tu[q] = bu[(size_t)gi * NN + g];
                        tv[q] = bv[(size_t)gi * NN + g];
                    }
                }
            }
        }
#pragma unroll
        for (int q = 0; q < 4; ++q) { sbu[r][c4 * 4 + q] = tu[q]; sbv[r][c4 * 4 + q] = tv[q]; }
    }
    __syncthreads();

    for (int idx = tid; idx < 18 * 66; idx += 256) {
        int r = idx / 66, c = idx - r * 66;
        int gi = ib - 1 + r, gj = jb - 1 + c;
        float kuo = 0.f, kvo = 0.f;
        if ((unsigned)gi < (unsigned)NN && (unsigned)gj < (unsigned)NN) {
            int lr = r + 1, lc = c + 3;
            float uc = sbu[lr][lc], ul = sbu[lr][lc - 1], ur = sbu[lr][lc + 1], ut = sbu[lr - 1][lc], ub = sbu[lr + 1][lc];
            float vc = sbv[lr][lc], vl = sbv[lr][lc - 1], vr = sbv[lr][lc + 1], vt = sbv[lr - 1][lc], vb = sbv[lr + 1][lc];
            float ADxu = 0.5f * (ur - ul), ADyu = 0.5f * (ub - ut);
            float ADxv = 0.5f * (vr - vl), ADyv = 0.5f * (vb - vt);
            float Lu = ul + ur + ut + ub - 4.f * uc;
            float Lv = vl + vr + vt + vb - 4.f * vc;
            float s = fabsf(uc) + fabsf(vc);
            float kuv = 0.25f * fabsf(0.5f * s * Lu) / (0.001f + 0.5f * (fabsf(ADxu) + fabsf(ADyu)));
            float kvv = 0.25f * fabsf(0.5f * s * Lv) / (0.001f + 0.5f * (fabsf(ADxv) + fabsf(ADyv)));
            float k1c = k1[(size_t)gi * NN + gj];
            kuo = fminf(kuv, k1c);
            kvo = fminf(kvv, k1c);
        }
        sku[r][c] = kuo;
        skv[r][c] = kvo;
    }
    __syncthreads();

    const int i = ib + threadIdx.y;
    const int j0 = jb + threadIdx.x * 4;
    float p6[6], pu[4], pd[4];
    float u6[6], uu[4], ud[4], v6[6], vu[4], vd[4], fx[4], fy[4], oun[4], ovn[4];
    load6e(p, i, j0, p6); load4e(p, i - 1, j0, pu); load4e(p, i + 1, j0, pd);
    load6z(u, i, j0, u6); load4z(u, i - 1, j0, uu); load4z(u, i + 1, j0, ud);
    load6z(v, i, j0, v6); load4z(v, i - 1, j0, vu); load4z(v, i + 1, j0, vd);
    load4z(Fx, i, j0, fx); load4z(Fy, i, j0, fy);
    const int lbr = threadIdx.y + 2, lkr = threadIdx.y + 1;
#pragma unroll
    for (int c = 0; c < 4; ++c) {
        int lbc = threadIdx.x * 4 + c + 4, lkc = threadIdx.x * 4 + c + 1;
        float buc = sbu[lbr][lbc], bul = sbu[lbr][lbc - 1], bur = sbu[lbr][lbc + 1], but = sbu[lbr - 1][lbc], bub = sbu[lbr + 1][lbc];
        float bvc = sbv[lbr][lbc], bvl = sbv[lbr][lbc - 1], bvr = sbv[lbr][lbc + 1], bvt = sbv[lbr - 1][lbc], bvb = sbv[lbr + 1][lbc];
        float kuc = sku[lkr][lkc], kul = sku[lkr][lkc - 1], kur = sku[lkr][lkc + 1], kut = sku[lkr - 1][lkc], kub = sku[lkr + 1][lkc];
        float kvc = skv[lkr][lkc], kvl = skv[lkr][lkc - 1], kvr = skv[lkr][lkc + 1], kvt = skv[lkr - 1][lkc], kvb = skv[lkr + 1][lkc];
        float uc = u6[c + 1], ul = u6[c], ur = u6[c + 2], ut = uu[c], ub = ud[c];
        float vc = v6[c + 1], vl = v6[c], vr = v6[c + 2], vt = vu[c], vb = vd[c];
        float ADxbu = 0.5f * (bur - bul), ADybu = 0.5f * (bub - but);
        float ADxbv = 0.5f * (bvr - bvl), ADybv = 0.5f * (bvb - bvt);
        float Lbu = bul + bur + but + bub - 4.f * buc;
        float Lbv = bvl + bvr + bvt + bvb - 4.f * bvc;
        float Lku = kul + kur + kut + kub - 4.f * kuc;
        float Lkv = kvl + kvr + kvt + kvb - 4.f * kvc;
        // product term uses ORIGINAL velocities
        float Luku = ul * kul + ur * kur + ut * kut + ub * kub - 4.f * uc * kuc;
        float Lvkv = vl * kvl + vr * kvr + vt * kvt + vb * kvb - 4.f * vc * kvc;
        float kx = 1.5f * (kuc * Lbu + Luku - buc * Lku);
        float ky = 1.5f * (kvc * Lbv + Lvkv - bvc * Lkv);
        float Grapx = 0.5f * (p6[c + 2] - p6[c]) * DT;
        float Grapy = 0.5f * (pd[c] - pu[c]) * DT;
        oun[c] = uc + kx * DT - buc * ADxbu * DT - bvc * ADybu * DT - Grapx - fx[c] * DT;
        ovn[c] = vc + ky * DT - buc * ADxbv * DT - bvc * ADybv * DT - Grapy - fy[c] * DT;
    }
    store4(un, i, j0, oun);
    store4(vn, i, j0, ovn);
}

// -------- fused: b = -div(un,vn)/DT + residual(p,b) + restrict to 1024/512/256/128 --------
__global__ __launch_bounds__(256) void k_rhs_res(const float* __restrict__ un, const float* __restrict__ vn,
                                                 const float* __restrict__ p, float* __restrict__ b,
                                                 float* __restrict__ r1024, float* __restrict__ r512,
                                                 float* __restrict__ r256, float* __restrict__ r128) {
    __shared__ float s512r[4][65];
    __shared__ float s256r[2][33];
    int tx = threadIdx.x, ty = threadIdx.y;
    int jt = blockIdx.x * 64 + tx;
    int it = blockIdx.y * 4 + ty;
    int j0 = jt * 4, i0 = it * 4;
    float bb[4][4];
#pragma unroll
    for (int r = 0; r < 4; ++r) {
        float u6[6], vu[4], vd[4];
        load6z(un, i0 + r, j0, u6);
        load4z(vn, i0 + r - 1, j0, vu);
        load4z(vn, i0 + r + 1, j0, vd);
#pragma unroll
        for (int c = 0; c < 4; ++c)
            bb[r][c] = -100.f * (0.5f * (u6[c + 2] - u6[c]) + 0.5f * (vd[c] - vu[c]));
        store4(b, i0 + r, j0, bb[r]);
    }
    float p6[6][6];
#pragma unroll
    for (int r = 0; r < 6; ++r) load6e(p, i0 - 1 + r, j0, p6[r]);
    float res[4][4];
#pragma unroll
    for (int r = 0; r < 4; ++r)
#pragma unroll
        for (int c = 0; c < 4; ++c) {
            float pc = p6[r + 1][c + 1];
            res[r][c] = p6[r][c + 1] + p6[r + 2][c + 1] + p6[r + 1][c] + p6[r + 1][c + 2] - 4.f * pc - bb[r][c];
        }
    float q00 = 0.25f * (res[0][0] + res[0][1] + res[1][0] + res[1][1]);
    float q01 = 0.25f * (res[0][2] + res[0][3] + res[1][2] + res[1][3]);
    float q10 = 0.25f * (res[2][0] + res[2][1] + res[3][0] + res[3][1]);
    float q11 = 0.25f * (res[2][2] + res[2][3] + res[3][2] + res[3][3]);
    int ci = it * 2, cj = jt * 2;
    *reinterpret_cast<float2*>(r1024 + (size_t)ci * 1024 + cj)       = make_float2(q00, q01);
    *reinterpret_cast<float2*>(r1024 + (size_t)(ci + 1) * 1024 + cj) = make_float2(q10, q11);
    float s = 0.25f * (q00 + q01 + q10 + q11);
    r512[(size_t)it * 512 + jt] = s;
    s512r[ty][tx] = s;
    __syncthreads();
    int tid = ty * 64 + tx;
    if (tid < 64) {
        int a = tid >> 5, c = tid & 31;
        float m = 0.25f * (s512r[2 * a][2 * c] + s512r[2 * a][2 * c + 1] + s512r[2 * a + 1][2 * c] + s512r[2 * a + 1][2 * c + 1]);
        r256[(size_t)(blockIdx.y * 2 + a) * 256 + blockIdx.x * 32 + c] = m;
        s256r[a][c] = m;
    }
    __syncthreads();
    if (tid < 16) {
        float m = 0.25f * (s256r[0][2 * tid] + s256r[0][2 * tid + 1] + s256r[1][2 * tid] + s256r[1][2 * tid + 1]);
        r128[(size_t)blockIdx.y * 128 + blockIdx.x * 16 + tid] = m;
    }
}

// ---------------- all coarse levels (<=128) in one block, from r128 ----------------
__global__ __launch_bounds__(1024) void k_small(const float* __restrict__ r128,
                                                float* __restrict__ w128_out,
                                                float* __restrict__ r2_out) {
    __shared__ float sr64[64 * 64];
    __shared__ float sr32[32 * 32];
    __shared__ float sr16[16 * 16];
    __shared__ float sr8[8 * 8];
    __shared__ float sr4[16];
    __shared__ float sr2[4];
    __shared__ float wa[64 * 64];
    __shared__ float wb[64 * 64];
    int t = threadIdx.x;

    for (int idx = t; idx < 64 * 64; idx += 1024) {
        int i = idx >> 6, j = idx & 63;
        const float* s0 = r128 + (2 * i) * 128 + 2 * j;
        sr64[idx] = 0.25f * (s0[0] + s0[1] + s0[128] + s0[129]);
    }
    __syncthreads();
    if (t < 32 * 32) {
        int i = t >> 5, j = t & 31;
        const float* s0 = sr64 + (2 * i) * 64 + 2 * j;
        sr32[t] = 0.25f * (s0[0] + s0[1] + s0[64] + s0[65]);
    }
    __syncthreads();
    if (t < 16 * 16) {
        int i = t >> 4, j = t & 15;
        const float* s0 = sr32 + (2 * i) * 32 + 2 * j;
        sr16[t] = 0.25f * (s0[0] + s0[1] + s0[32] + s0[33]);
    }
    __syncthreads();
    if (t < 64) {
        int i = t >> 3, j = t & 7;
        const float* s0 = sr16 + (2 * i) * 16 + 2 * j;
        sr8[t] = 0.25f * (s0[0] + s0[1] + s0[16] + s0[17]);
    }
    __syncthreads();
    if (t < 16) {
        int i = t >> 2, j = t & 3;
        const float* s0 = sr8 + (2 * i) * 8 + 2 * j;
        sr4[t] = 0.25f * (s0[0] + s0[1] + s0[8] + s0[9]);
    }
    __syncthreads();
    if (t < 4) {
        int i = t >> 1, j = t & 1;
        const float* s0 = sr4 + (2 * i) * 4 + 2 * j;
        sr2[t] = 0.25f * (s0[0] + s0[1] + s0[4] + s0[5]);
        r2_out[t] = sr2[t];
        float ws = -0.25f * sr2[t];
        wa[(2 * i) * 4 + 2 * j] = ws;
        wa[(2 * i) * 4 + 2 * j + 1] = ws;
        wa[(2 * i + 1) * 4 + 2 * j] = ws;
        wa[(2 * i + 1) * 4 + 2 * j + 1] = ws;
    }
    __syncthreads();

    auto step = [&](const float* win, const float* rl, float* wout, int s) {
        for (int idx = t; idx < s * s; idx += 1024) {
            int i = idx / s, j = idx - i * s;
            float up = i > 0 ? win[(i - 1) * s + j] : 0.f;
            float dn = i < s - 1 ? win[(i + 1) * s + j] : 0.f;
            float lf = j > 0 ? win[i * s + j - 1] : 0.f;
            float rt = j < s - 1 ? win[i * s + j + 1] : 0.f;
            float ws = 0.25f * (up + dn + lf + rt - rl[idx]);
            int o = 2 * s;
            wout[(2 * i) * o + 2 * j] = ws;
            wout[(2 * i) * o + 2 * j + 1] = ws;
            wout[(2 * i + 1) * o + 2 * j] = ws;
            wout[(2 * i + 1) * o + 2 * j + 1] = ws;
        }
    };
    step(wa, sr4, wb, 4);
    __syncthreads();
    step(wb, sr8, wa, 8);
    __syncthreads();
    step(wa, sr16, wb, 16);
    __syncthreads();
    step(wb, sr32, wa, 32);
    __syncthreads();
    step(wa, sr64, w128_out, 64);
}

// ======== fused p-update (16-row tile): prolong chain in LDS -> p_new (+halo)
//          + next residual + restrict 1024/512/256/128  (LAST: out_p/out_w + projection) ========
template <bool LAST>
__global__ __launch_bounds__(256) void k_pupd5(
    const float* __restrict__ p, const float* __restrict__ b,
    const float* __restrict__ w128, const float* __restrict__ r128,
    const float* __restrict__ r256, const float* __restrict__ r512,
    const float* __restrict__ r1024,
    float* __restrict__ pdst,
    float* __restrict__ o1024, float* __restrict__ o512,
    float* __restrict__ o256, float* __restrict__ o128,
    float* __restrict__ wout, float* __restrict__ un, float* __restrict__ vn)
{
    __shared__ float sw[5][15];
    __shared__ float s128[3][13];
    __shared__ float s256[4][21];
    __shared__ float sS[6][37];
    __shared__ float ws[10][69];
    __shared__ float pmid[20][137];
    __shared__ float pnew[18][131];
    __shared__ float sq[8][65];
    __shared__ float red[4][33];
    __shared__ float red2[2][17];

    const int jb = blockIdx.x * 128;
    const int ib = blockIdx.y * 16;
    const int tid = threadIdx.y * 32 + threadIdx.x;
    const int r1 = ib / 2 - 1,  c1 = jb / 2 - 2;   // ws 10x68
    const int r2 = ib / 4 - 1,  c2 = jb / 4 - 2;   // sS 6x36
    const int r3 = ib / 8 - 1,  c3 = jb / 8 - 2;   // s256 4x20
    const int r4 = ib / 16 - 1, c4 = jb / 16 - 2;  // s128 3x12
    const int r5 = ib / 16 - 2, c5 = jb / 16 - 3;  // sw 5x14

    if (tid < 5 * 14) {
        int r = tid / 14, c = tid - (tid / 14) * 14;
        int x = r5 + r, y = c5 + c;
        sw[r][c] = ((unsigned)x < 128u && (unsigned)y < 128u) ? w128[x * 128 + y] : 0.f;
    }
    __syncthreads();
    if (tid < 3 * 12) {
        int r = tid / 12, c = tid - (tid / 12) * 12;
        int x = r4 + r, y = c4 + c;
        float val = 0.f;
        if ((unsigned)x < 128u && (unsigned)y < 128u) {
            int lr = x - r5, lc = y - c5;
            float s = 0.f;
            if (x > 0)   s += sw[lr - 1][lc];
            if (x < 127) s += sw[lr + 1][lc];
            if (y > 0)   s += sw[lr][lc - 1];
            if (y < 127) s += sw[lr][lc + 1];
            val = 0.25f * (s - r128[x * 128 + y]);
        }
        s128[r][c] = val;
    }
    __syncthreads();
    if (tid < 4 * 20) {
        int r = tid / 20, c = tid - (tid / 20) * 20;
        int x = r3 + r, y = c3 + c;
        float val = 0.f;
        if ((unsigned)x < 256u && (unsigned)y < 256u) {
            float s = 0.f;
            if (x > 0)   s += s128[((x - 1) >> 1) - r4][(y >> 1) - c4];
            if (x < 255) s += s128[((x + 1) >> 1) - r4][(y >> 1) - c4];
            if (y > 0)   s += s128[(x >> 1) - r4][((y - 1) >> 1) - c4];
            if (y < 255) s += s128[(x >> 1) - r4][((y + 1) >> 1) - c4];
            val = 0.25f * (s - r256[x * 256 + y]);
        }
        s256[r][c] = val;
    }
    __syncthreads();
    if (tid < 6 * 36) {
        int r = tid / 36, c = tid - (tid / 36) * 36;
        int x = r2 + r, y = c2 + c;
        float val = 0.f;
        if ((unsigned)x < 512u && (unsigned)y < 512u) {
            float s = 0.f;
            if (x > 0)   s += s256[((x - 1) >> 1) - r3][(y >> 1) - c3];
            if (x < 511) s += s256[((x + 1) >> 1) - r3][(y >> 1) - c3];
            if (y > 0)   s += s256[(x >> 1) - r3][((y - 1) >> 1) - c3];
            if (y < 511) s += s256[(x >> 1) - r3][((y + 1) >> 1) - c3];
            val = 0.25f * (s - r512[(size_t)x * 512 + y]);
        }
        sS[r][c] = val;
    }
    __syncthreads();
    for (int idx = tid; idx < 10 * 68; idx += 256) {
        int r = idx / 68, c = idx - r * 68;
        int x = r1 + r, y = c1 + c;
        float val = 0.f;
        if ((unsigned)x < 1024u && (unsigned)y < 1024u) {
            float s = 0.f;
            if (x > 0)    s += sS[((x - 1) >> 1) - r2][(y >> 1) - c2];
            if (x < 1023) s += sS[((x + 1) >> 1) - r2][(y >> 1) - c2];
            if (y > 0)    s += sS[(x >> 1) - r2][((y - 1) >> 1) - c2];
            if (y < 1023) s += sS[(x >> 1) - r2][((y + 1) >> 1) - c2];
            val = 0.25f * (s - r1024[(size_t)x * 1024 + y]);
        }
        ws[r][c] = val;
    }
    __syncthreads();
    // pmid = p - up(S1024s): rows ib-2..ib+17, cols stored jb-4..jb+131 (valid jb-2..jb+129)
    for (int idx = tid; idx < 20 * 34; idx += 256) {
        int r = idx / 34, q = idx - r * 34;
        int gi = ib - 2 + r;
        int gj0 = jb - 4 + q * 4;
        float vals[4] = {0.f, 0.f, 0.f, 0.f};
        if ((unsigned)gi < (unsigned)NN) {
            if (gj0 >= 0 && gj0 + 3 < NN) {
                float4 pv = *reinterpret_cast<const float4*>(p + (size_t)gi * NN + gj0);
                vals[0] = pv.x; vals[1] = pv.y; vals[2] = pv.z; vals[3] = pv.w;
            } else {
#pragma unroll
                for (int q4 = 0; q4 < 4; ++q4) {
                    int gj = gj0 + q4;
                    vals[q4] = ((unsigned)gj < (unsigned)NN) ? p[(size_t)gi * NN + gj] : 0.f;
                }
            }
        }
#pragma unroll
        for (int q4 = 0; q4 < 4; ++q4) {
            int gj = gj0 + q4;
            float m = 0.f;
            if ((unsigned)gi < (unsigned)NN && (unsigned)gj < (unsigned)NN &&
                gj >= jb - 2 && gj <= jb + 129) {
                m = vals[q4] - ws[(gi >> 1) - r1][(gj >> 1) - c1];
            }
            pmid[r][q * 4 + q4] = m;
        }
    }
    __syncthreads();
    // p_new = 0.25*(edge-sum(pmid) - b): rows ib-1..ib+16, cols jb-1..jb+128
    for (int idx = tid; idx < 18 * 130; idx += 256) {
        int r = idx / 130, c = idx - r * 130;
        int gi = ib - 1 + r, gj = jb - 1 + c;
        float val = 0.f;
        if ((unsigned)gi < (unsigned)NN && (unsigned)gj < (unsigned)NN) {
            int iu = gi > 0 ? gi - 1 : 0;
            int idn = gi < NN - 1 ? gi + 1 : NN - 1;
            int jl = gj > 0 ? gj - 1 : 0;
            int jr = gj < NN - 1 ? gj + 1 : NN - 1;
            float s = pmid[iu - (ib - 2)][gj - (jb - 4)] + pmid[idn - (ib - 2)][gj - (jb - 4)]
                    + pmid[gi - (ib - 2)][jl - (jb - 4)] + pmid[gi - (ib - 2)][jr - (jb - 4)];
            val = 0.25f * (s - b[(size_t)gi * NN + gj]);
        }
        pnew[r][c] = val;
    }
    __syncthreads();

    const int j0 = jb + threadIdx.x * 4;
#pragma unroll
    for (int rr = 0; rr < 2; ++rr) {
        int i = ib + threadIdx.y + rr * 8;
        int lr = i - (ib - 1);
        int lc = j0 - (jb - 1);
        *reinterpret_cast<float4*>(pdst + (size_t)i * NN + j0) =
            make_float4(pnew[lr][lc], pnew[lr][lc + 1], pnew[lr][lc + 2], pnew[lr][lc + 3]);
    }

    if (LAST) {
        const float DT = 0.01f;
#pragma unroll
        for (int rr = 0; rr < 2; ++rr) {
            int i = ib + threadIdx.y + rr * 8;
            int lr = i - (ib - 1);
            int wr = (i >> 1) - r1;
            float ow[4];
#pragma unroll
            for (int c = 0; c < 4; ++c) ow[c] = ws[wr][((j0 + c) >> 1) - c1];
            store4(wout, i, j0, ow);
            float4 uu = *reinterpret_cast<float4*>(un + (size_t)i * NN + j0);
            float4 vv = *reinterpret_cast<float4*>(vn + (size_t)i * NN + j0);
            float ou[4] = {uu.x, uu.y, uu.z, uu.w};
            float ov[4] = {vv.x, vv.y, vv.z, vv.w};
            int iu = (i > 0 ? i - 1 : 0) - (ib - 1);
            int idn = (i < NN - 1 ? i + 1 : NN - 1) - (ib - 1);
#pragma unroll
            for (int c = 0; c < 4; ++c) {
                int j = j0 + c;
                int jl = (j > 0 ? j - 1 : 0) - (jb - 1);
                int jr = (j < NN - 1 ? j + 1 : NN - 1) - (jb - 1);
                int lcc = j - (jb - 1);
                ou[c] -= 0.5f * (pnew[lr][jr] - pnew[lr][jl]) * DT;
                ov[c] -= 0.5f * (pnew[idn][lcc] - pnew[iu][lcc]) * DT;
            }
            store4(un, i, j0, ou);
            store4(vn, i, j0, ov);
        }
    } else {
        // next residual on p_new + restrict chain: coarse-1024 region 8x64, 2 pts/thread
#pragma unroll
        for (int rr = 0; rr < 2; ++rr) {
            int cr = (tid >> 6) + rr * 4;
            int cc = tid & 63;
            float q = 0.f;
#pragma unroll
            for (int dr = 0; dr < 2; ++dr) {
#pragma unroll
                for (int dc = 0; dc < 2; ++dc) {
                    int i2 = ib + 2 * cr + dr, j2 = jb + 2 * cc + dc;
                    int lr2 = i2 - (ib - 1), lc2 = j2 - (jb - 1);
                    int iu2 = (i2 > 0 ? i2 - 1 : 0) - (ib - 1);
                    int id2 = (i2 < NN - 1 ? i2 + 1 : NN - 1) - (ib - 1);
                    int jl2 = (j2 > 0 ? j2 - 1 : 0) - (jb - 1);
                    int jr2 = (j2 < NN - 1 ? j2 + 1 : NN - 1) - (jb - 1);
                    q += pnew[iu2][lc2] + pnew[id2][lc2] + pnew[lr2][jl2] + pnew[lr2][jr2]
                       - 4.f * pnew[lr2][lc2] - b[(size_t)i2 * NN + j2];
                }
            }
            q *= 0.25f;
            sq[cr][cc] = q;
            o1024[(size_t)(ib / 2 + cr) * 1024 + jb / 2 + cc] = q;
        }
        __syncthreads();
        if (tid < 128) {
            int rr = tid >> 5, cc = tid & 31;
            float m = 0.25f * (sq[2 * rr][2 * cc] + sq[2 * rr][2 * cc + 1] +
                               sq[2 * rr + 1][2 * cc] + sq[2 * rr + 1][2 * cc + 1]);
            o512[(size_t)(ib / 4 + rr) * 512 + jb / 4 + cc] = m;
            red[rr][cc] = m;
        }
        __syncthreads();
        if (tid < 32) {
            int rr = tid >> 4, cc = tid & 15;
            float m = 0.25f * (red[2 * rr][2 * cc] + red[2 * rr][2 * cc + 1] +
                               red[2 * rr + 1][2 * cc] + red[2 * rr + 1][2 * cc + 1]);
            o256[(size_t)(ib / 8 + rr) * 256 + jb / 8 + cc] = m;
            red2[rr][cc] = m;
        }
        __syncthreads();
        if (tid < 8) {
            float m = 0.25f * (red2[0][2 * tid] + red2[0][2 * tid + 1] +
                               red2[1][2 * tid] + red2[1][2 * tid + 1]);
            o128[(size_t)(ib / 16) * 128 + jb / 16 + tid] = m;
        }
    }
}

extern "C" void kernel_launch(void* const* d_in, const int* in_sizes, int n_in,
                              void* d_out, int out_size, void* d_ws, size_t ws_size,
                              hipStream_t stream) {
    const float* u  = (const float*)d_in[0];
    const float* v  = (const float*)d_in[1];
    const float* p  = (const float*)d_in[2];
    const float* Fx = (const float*)d_in[3];
    const float* Fy = (const float*)d_in[4];
    const float* k1 = (const float*)d_in[5];

    float* out = (float*)d_out;
    float* out_u = out;
    float* out_v = out + (size_t)NN2;
    float* out_p = out + 2 * (size_t)NN2;
    float* out_w = out + 3 * (size_t)NN2;
    float* out_r = out + 4 * (size_t)NN2;

    float* wsb = (float*)d_ws;
    float* b  = wsb;
    float* pA = wsb + (size_t)NN2;
    float* pB = wsb + 2 * (size_t)NN2;
    float* base = wsb + 3 * (size_t)NN2;
    float* rA1024 = base;
    float* rA512  = rA1024 + 1024 * 1024;
    float* rA256  = rA512 + 512 * 512;
    float* rA128  = rA256 + 256 * 256;
    float* rB1024 = rA128 + 128 * 128;
    float* rB512  = rB1024 + 1024 * 1024;
    float* rB256  = rB512 + 512 * 512;
    float* rB128  = rB256 + 256 * 256;
    float* w128   = rB128 + 128 * 128;

    // b_u/b_v live in not-yet-needed output regions (dead before w/p are produced)
    float* bu = out_w;
    float* bv = out_p;

    dim3 blkT(16, 16);
    dim3 gT(32, 128);       // momentum: 64x16 tiles
    dim3 blkR(64, 4);
    dim3 gR(8, 128);        // rhs_res: 256x16 fine tiles
    dim3 blkP(32, 8);
    dim3 gP(16, 128);       // pupd5: 128x16 fine tiles

    // momentum (split pair, odd-stride LDS)
    k_pred_f<<<gT, blkT, 0, stream>>>(u, v, k1, p, bu, bv);
    k_corr_f<<<gT, blkT, 0, stream>>>(u, v, k1, p, bu, bv, Fx, Fy, out_u, out_v);
    // b + initial residual pyramid (A) incl. r128
    k_rhs_res<<<gR, blkR, 0, stream>>>(out_u, out_v, p, b, rA1024, rA512, rA256, rA128);

    const float* pcur = p;
    for (int it = 0; it < 5; ++it) {
        const bool useA = (it % 2 == 0);
        const float* R1024 = useA ? rA1024 : rB1024;
        const float* R512  = useA ? rA512  : rB512;
        const float* R256  = useA ? rA256  : rB256;
        const float* R128  = useA ? rA128  : rB128;
        float* O1024 = useA ? rB1024 : rA1024;
        float* O512  = useA ? rB512  : rA512;
        float* O256  = useA ? rB256  : rA256;
        float* O128  = useA ? rB128  : rA128;

        k_small<<<1, 1024, 0, stream>>>(R128, w128, out_r);
        if (it < 4) {
            float* pdst = (it & 1) ? pB : pA;
            k_pupd5<false><<<gP, blkP, 0, stream>>>(pcur, b, w128, R128, R256, R512, R1024,
                                                    pdst, O1024, O512, O256, O128,
                                                    nullptr, nullptr, nullptr);
            pcur = pdst;
        } else {
            k_pupd5<true><<<gP, blkP, 0, stream>>>(pcur, b, w128, R128, R256, R512, R1024,
                                                   out_p, nullptr, nullptr, nullptr, nullptr,
                                                   out_w, out_u, out_v);
        }
    }
}